// Round 1
// baseline (18560.428 us; speedup 1.0000x reference)
//
#include <hip/hip_runtime.h>
#include <math.h>
#include <float.h>

// Decoder: 32-step greedy GRU decode. B=64, H=E=1024, L=2, V=32000, T=32.
// fp32 baseline. State layout: transposed [k][64] so lane=batch.

#define B_ 64
#define H_ 1024
#define V_ 32000
#define T_ 32
#define R3H 3072

// workspace offsets (in 4-byte elements)
#define XT_OFF   0         // xT [1024][64]
#define HT_OFF   65536     // hT [2][1024][64]
#define G_OFF    196608    // gbuf [6144][64]
#define PV_OFF   589824    // pval [1000][64]
#define PIDX_OFF 653824    // pidx [1000][64] (int)
#define TOK_OFF  717824    // tok [64] (int)

#define OUT_H_OFF 65536000L  // 64*32*32000

__global__ void k_init(const float* __restrict__ enc_h, float* __restrict__ ws,
                       int* __restrict__ wsI) {
  int n = blockIdx.x * 256 + threadIdx.x;         // 512 blocks -> 131072 = 2*1024*64
  int b = n & 63, k = (n >> 6) & 1023, l = n >> 16;
  ws[HT_OFF + l * 65536 + k * 64 + b] = enc_h[l * (B_ * H_) + b * H_ + k];
  if (n < B_) wsI[TOK_OFF + n] = 0;               // START token
}

// Finalize argmax of previous step (1000 block-partials), then gather+relu embedding.
__global__ void k_argmax_embed(const float* __restrict__ emb, float* __restrict__ ws,
                               int* __restrict__ wsI, int do_argmax) {
  int tid = threadIdx.x;                          // 1024 threads, 1 block
  if (do_argmax && tid < B_) {
    float best = -FLT_MAX; int bi = 0;
    for (int i = 0; i < 1000; ++i) {              // ascending i == ascending v; strict > keeps first
      float v = ws[PV_OFF + i * 64 + tid];
      if (v > best) { best = v; bi = wsI[PIDX_OFF + i * 64 + tid]; }
    }
    wsI[TOK_OFF + tid] = bi;
  }
  __syncthreads();
  int b = tid >> 4, tl = tid & 15;
  const float* erow = emb + (long)wsI[TOK_OFF + b] * H_;
  #pragma unroll
  for (int c = 0; c < 16; ++c) {
    int e = c * 64 + tl * 4;
    float4 v = *(const float4*)(erow + e);
    ws[XT_OFF + (e + 0) * 64 + b] = fmaxf(v.x, 0.f);
    ws[XT_OFF + (e + 1) * 64 + b] = fmaxf(v.y, 0.f);
    ws[XT_OFF + (e + 2) * 64 + b] = fmaxf(v.z, 0.f);
    ws[XT_OFF + (e + 3) * 64 + b] = fmaxf(v.w, 0.f);
  }
}

// GRU gate gemms: rows 0..3071 = W_ih . xT (+b_ih), rows 3072..6143 = W_hh . hT (+b_hh).
// 16 rows/block (4 waves x 4 rows), K=1024 in 8 LDS-staged tiles of 128.
__global__ __launch_bounds__(256) void k_gemv_gru(
    const float* __restrict__ w_ih, const float* __restrict__ w_hh,
    const float* __restrict__ b_ih, const float* __restrict__ b_hh,
    const float* __restrict__ srcx, const float* __restrict__ srch,
    float* __restrict__ g) {
  __shared__ __align__(16) float st[8192];        // [128 k][64 b]
  int tid = threadIdx.x;
  int wave = __builtin_amdgcn_readfirstlane(tid >> 6);
  int lane = tid & 63;
  int row0 = blockIdx.x * 16;
  bool use_x = row0 < R3H;
  const float* W    = use_x ? (w_ih + (long)row0 * 1024) : (w_hh + (long)(row0 - R3H) * 1024);
  const float* src  = use_x ? srcx : srch;
  const float* bias = use_x ? (b_ih + row0) : (b_hh + row0 - R3H);
  float acc[4] = {0.f, 0.f, 0.f, 0.f};
  const float* Wbase = W + (long)(wave * 4) * 1024;
  for (int kt = 0; kt < 8; ++kt) {
    const float4* sp = (const float4*)(src + kt * 8192);
    float4* stp = (float4*)st;
    #pragma unroll
    for (int i = 0; i < 8; ++i) stp[tid + i * 256] = sp[tid + i * 256];
    __syncthreads();
    const float* Wt = Wbase + kt * 128;
    for (int k = 0; k < 128; k += 4) {
      float s0 = st[(k + 0) * 64 + lane], s1 = st[(k + 1) * 64 + lane];
      float s2 = st[(k + 2) * 64 + lane], s3 = st[(k + 3) * 64 + lane];
      #pragma unroll
      for (int jj = 0; jj < 4; ++jj) {
        float4 w = *(const float4*)(Wt + (long)jj * 1024 + k);
        acc[jj] = fmaf(w.w, s3, fmaf(w.z, s2, fmaf(w.y, s1, fmaf(w.x, s0, acc[jj]))));
      }
    }
    __syncthreads();
  }
  #pragma unroll
  for (int jj = 0; jj < 4; ++jj) {
    int r = wave * 4 + jj;
    g[(long)(row0 + r) * 64 + lane] = acc[jj] + bias[r];
  }
}

// Pointwise GRU gate math; updates hT[l] in place (torch gate order r,z,n).
__global__ void k_gates(const float* __restrict__ g, float* __restrict__ hT) {
  int n = blockIdx.x * 256 + threadIdx.x;         // 256 blocks -> 65536 = 1024*64
  int b = n & 63, j = n >> 6;
  float ir = g[(long)j * 64 + b];
  float iz = g[(long)(j + 1024) * 64 + b];
  float in = g[(long)(j + 2048) * 64 + b];
  float hr = g[(long)(3072 + j) * 64 + b];
  float hz = g[(long)(4096 + j) * 64 + b];
  float hn = g[(long)(5120 + j) * 64 + b];
  float r = 1.f / (1.f + expf(-(ir + hr)));
  float z = 1.f / (1.f + expf(-(iz + hz)));
  float nn = tanhf(in + r * hn);
  float ho = hT[(long)j * 64 + b];
  hT[(long)j * 64 + b] = (1.f - z) * nn + z * ho;
}

// Logits gemv: 32 rows/block (4 waves x 8 rows) over V=32000 -> 1000 blocks.
// Writes logits to d_out[b][t][v], emits per-block argmax partials.
__global__ __launch_bounds__(256) void k_logits(
    const float* __restrict__ Wo, const float* __restrict__ bo,
    const float* __restrict__ src, float* __restrict__ ws, int* __restrict__ wsI,
    float* __restrict__ dout, int t) {
  __shared__ __align__(16) float st[8192];
  __shared__ float redv[256];
  __shared__ int   redi[256];
  int tid = threadIdx.x;
  int wave = __builtin_amdgcn_readfirstlane(tid >> 6);
  int lane = tid & 63;
  int row0 = blockIdx.x * 32;
  float acc[8] = {0.f, 0.f, 0.f, 0.f, 0.f, 0.f, 0.f, 0.f};
  const float* Wbase = Wo + (long)(row0 + wave * 8) * 1024;
  for (int kt = 0; kt < 8; ++kt) {
    const float4* sp = (const float4*)(src + kt * 8192);
    float4* stp = (float4*)st;
    #pragma unroll
    for (int i = 0; i < 8; ++i) stp[tid + i * 256] = sp[tid + i * 256];
    __syncthreads();
    const float* Wt = Wbase + kt * 128;
    for (int k = 0; k < 128; k += 4) {
      float s0 = st[(k + 0) * 64 + lane], s1 = st[(k + 1) * 64 + lane];
      float s2 = st[(k + 2) * 64 + lane], s3 = st[(k + 3) * 64 + lane];
      #pragma unroll
      for (int jj = 0; jj < 8; ++jj) {
        float4 w = *(const float4*)(Wt + (long)jj * 1024 + k);
        acc[jj] = fmaf(w.w, s3, fmaf(w.z, s2, fmaf(w.y, s1, fmaf(w.x, s0, acc[jj]))));
      }
    }
    __syncthreads();
  }
  float bestv = -FLT_MAX; int besti = 0;
  long obase = (long)lane * (T_ * (long)V_) + (long)t * V_;
  #pragma unroll
  for (int jj = 0; jj < 8; ++jj) {
    int v = row0 + wave * 8 + jj;                 // ascending within wave
    float val = acc[jj] + bo[v];
    dout[obase + v] = val;
    if (val > bestv) { bestv = val; besti = v; }  // strict > keeps first on ties
  }
  redv[wave * 64 + lane] = bestv;
  redi[wave * 64 + lane] = besti;
  __syncthreads();
  if (tid < 64) {
    float bv = redv[tid]; int bi = redi[tid];
    #pragma unroll
    for (int w = 1; w < 4; ++w) {                 // ascending wave == ascending v
      float v2 = redv[w * 64 + tid];
      if (v2 > bv) { bv = v2; bi = redi[w * 64 + tid]; }
    }
    ws[PV_OFF + blockIdx.x * 64 + tid] = bv;
    wsI[PIDX_OFF + blockIdx.x * 64 + tid] = bi;
  }
}

__global__ void k_final(const float* __restrict__ ws, float* __restrict__ dout) {
  int n = blockIdx.x * 256 + threadIdx.x;         // 512 blocks -> 131072
  int k = n & 1023, b = (n >> 10) & 63, l = n >> 16;
  dout[OUT_H_OFF + (long)l * (B_ * H_) + (long)b * H_ + k] =
      ws[HT_OFF + l * 65536 + k * 64 + b];
}

extern "C" void kernel_launch(void* const* d_in, const int* in_sizes, int n_in,
                              void* d_out, int out_size, void* d_ws, size_t ws_size,
                              hipStream_t stream) {
  const float* enc_h = (const float*)d_in[1];
  const float* emb   = (const float*)d_in[2];
  const float* w_ih  = (const float*)d_in[3];
  const float* w_hh  = (const float*)d_in[4];
  const float* b_ih  = (const float*)d_in[5];
  const float* b_hh  = (const float*)d_in[6];
  const float* out_w = (const float*)d_in[7];
  const float* out_b = (const float*)d_in[8];
  float* ws  = (float*)d_ws;
  int*   wsI = (int*)d_ws;
  float* out = (float*)d_out;

  k_init<<<512, 256, 0, stream>>>(enc_h, ws, wsI);
  for (int t = 0; t < T_; ++t) {
    k_argmax_embed<<<1, 1024, 0, stream>>>(emb, ws, wsI, t > 0);
    for (int l = 0; l < 2; ++l) {
      const float* sx = (l == 0) ? (ws + XT_OFF) : (ws + HT_OFF);  // layer1 input = hT0
      float* hT = ws + HT_OFF + l * 65536;
      k_gemv_gru<<<384, 256, 0, stream>>>(w_ih + (long)l * R3H * 1024,
                                          w_hh + (long)l * R3H * 1024,
                                          b_ih + l * R3H, b_hh + l * R3H,
                                          sx, hT, ws + G_OFF);
      k_gates<<<256, 256, 0, stream>>>(ws + G_OFF, hT);
    }
    k_logits<<<1000, 256, 0, stream>>>(out_w, out_b, ws + HT_OFF + 65536,
                                       ws, wsI, out, t);
  }
  k_final<<<512, 256, 0, stream>>>(ws, out);
}

// Round 2
// 11207.200 us; speedup vs baseline: 1.6561x; 1.6561x over previous
//
#include <hip/hip_runtime.h>
#include <math.h>
#include <float.h>

// Decoder: 32-step greedy GRU decode. B=64, H=E=1024, L=2, V=32000, T=32.
// fp32 baseline. State layout: transposed [k][64] so lane=batch.
// R2: wave-parallel argmax finalize (was 303us serial-wave loop -> ~10us).

#define B_ 64
#define H_ 1024
#define V_ 32000
#define T_ 32
#define R3H 3072

// workspace offsets (in 4-byte elements)
#define XT_OFF   0         // xT [1024][64]
#define HT_OFF   65536     // hT [2][1024][64]
#define G_OFF    196608    // gbuf [6144][64]
#define PV_OFF   589824    // pval [1000][64]
#define PIDX_OFF 653824    // pidx [1000][64] (int)
#define TOK_OFF  717824    // tok [64] (int)

#define OUT_H_OFF 65536000L  // 64*32*32000

__global__ void k_init(const float* __restrict__ enc_h, float* __restrict__ ws,
                       int* __restrict__ wsI) {
  int n = blockIdx.x * 256 + threadIdx.x;         // 512 blocks -> 131072 = 2*1024*64
  int b = n & 63, k = (n >> 6) & 1023, l = n >> 16;
  ws[HT_OFF + l * 65536 + k * 64 + b] = enc_h[l * (B_ * H_) + b * H_ + k];
  if (n < B_) wsI[TOK_OFF + n] = 0;               // START token
}

// Finalize argmax of previous step (1000 block-partials), then gather+relu embedding.
// 1024 threads: 16 chunks x 64 batches; each thread scans ~63 strided partials
// (independent loads -> pipelined), then 16-way LDS reduce per batch.
__global__ void k_argmax_embed(const float* __restrict__ emb, float* __restrict__ ws,
                               int* __restrict__ wsI, int do_argmax) {
  __shared__ float sv[1024];
  __shared__ int   si[1024];
  int tid = threadIdx.x;                          // 1024 threads, 1 block
  if (do_argmax) {
    int b = tid & 63, c = tid >> 6;               // chunk c in [0,16)
    float best = -FLT_MAX; int bi = 0x7fffffff;
    for (int i = c; i < 1000; i += 16) {          // ascending i within chunk
      float v  = ws[PV_OFF + i * 64 + b];
      int   ix = wsI[PIDX_OFF + i * 64 + b];
      if (v > best || (v == best && ix < bi)) { best = v; bi = ix; }
    }
    sv[c * 64 + b] = best;
    si[c * 64 + b] = bi;
    __syncthreads();
    if (tid < 64) {
      float bv = sv[tid]; int bix = si[tid];
      #pragma unroll
      for (int c2 = 1; c2 < 16; ++c2) {
        float v2 = sv[c2 * 64 + tid]; int i2 = si[c2 * 64 + tid];
        if (v2 > bv || (v2 == bv && i2 < bix)) { bv = v2; bix = i2; }
      }
      wsI[TOK_OFF + tid] = bix;                   // jnp.argmax: lowest index on ties
    }
  }
  __syncthreads();
  int b = tid >> 4, tl = tid & 15;
  const float* erow = emb + (long)wsI[TOK_OFF + b] * H_;
  #pragma unroll
  for (int c = 0; c < 16; ++c) {
    int e = c * 64 + tl * 4;
    float4 v = *(const float4*)(erow + e);
    ws[XT_OFF + (e + 0) * 64 + b] = fmaxf(v.x, 0.f);
    ws[XT_OFF + (e + 1) * 64 + b] = fmaxf(v.y, 0.f);
    ws[XT_OFF + (e + 2) * 64 + b] = fmaxf(v.z, 0.f);
    ws[XT_OFF + (e + 3) * 64 + b] = fmaxf(v.w, 0.f);
  }
}

// GRU gate gemms: rows 0..3071 = W_ih . xT (+b_ih), rows 3072..6143 = W_hh . hT (+b_hh).
// 16 rows/block (4 waves x 4 rows), K=1024 in 8 LDS-staged tiles of 128.
__global__ __launch_bounds__(256) void k_gemv_gru(
    const float* __restrict__ w_ih, const float* __restrict__ w_hh,
    const float* __restrict__ b_ih, const float* __restrict__ b_hh,
    const float* __restrict__ srcx, const float* __restrict__ srch,
    float* __restrict__ g) {
  __shared__ __align__(16) float st[8192];        // [128 k][64 b]
  int tid = threadIdx.x;
  int wave = __builtin_amdgcn_readfirstlane(tid >> 6);
  int lane = tid & 63;
  int row0 = blockIdx.x * 16;
  bool use_x = row0 < R3H;
  const float* W    = use_x ? (w_ih + (long)row0 * 1024) : (w_hh + (long)(row0 - R3H) * 1024);
  const float* src  = use_x ? srcx : srch;
  const float* bias = use_x ? (b_ih + row0) : (b_hh + row0 - R3H);
  float acc[4] = {0.f, 0.f, 0.f, 0.f};
  const float* Wbase = W + (long)(wave * 4) * 1024;
  for (int kt = 0; kt < 8; ++kt) {
    const float4* sp = (const float4*)(src + kt * 8192);
    float4* stp = (float4*)st;
    #pragma unroll
    for (int i = 0; i < 8; ++i) stp[tid + i * 256] = sp[tid + i * 256];
    __syncthreads();
    const float* Wt = Wbase + kt * 128;
    for (int k = 0; k < 128; k += 4) {
      float s0 = st[(k + 0) * 64 + lane], s1 = st[(k + 1) * 64 + lane];
      float s2 = st[(k + 2) * 64 + lane], s3 = st[(k + 3) * 64 + lane];
      #pragma unroll
      for (int jj = 0; jj < 4; ++jj) {
        float4 w = *(const float4*)(Wt + (long)jj * 1024 + k);
        acc[jj] = fmaf(w.w, s3, fmaf(w.z, s2, fmaf(w.y, s1, fmaf(w.x, s0, acc[jj]))));
      }
    }
    __syncthreads();
  }
  #pragma unroll
  for (int jj = 0; jj < 4; ++jj) {
    int r = wave * 4 + jj;
    g[(long)(row0 + r) * 64 + lane] = acc[jj] + bias[r];
  }
}

// Pointwise GRU gate math; updates hT[l] in place (torch gate order r,z,n).
__global__ void k_gates(const float* __restrict__ g, float* __restrict__ hT) {
  int n = blockIdx.x * 256 + threadIdx.x;         // 256 blocks -> 65536 = 1024*64
  int b = n & 63, j = n >> 6;
  float ir = g[(long)j * 64 + b];
  float iz = g[(long)(j + 1024) * 64 + b];
  float in = g[(long)(j + 2048) * 64 + b];
  float hr = g[(long)(3072 + j) * 64 + b];
  float hz = g[(long)(4096 + j) * 64 + b];
  float hn = g[(long)(5120 + j) * 64 + b];
  float r = 1.f / (1.f + expf(-(ir + hr)));
  float z = 1.f / (1.f + expf(-(iz + hz)));
  float nn = tanhf(in + r * hn);
  float ho = hT[(long)j * 64 + b];
  hT[(long)j * 64 + b] = (1.f - z) * nn + z * ho;
}

// Logits gemv: 32 rows/block (4 waves x 8 rows) over V=32000 -> 1000 blocks.
// Writes logits to d_out[b][t][v], emits per-block argmax partials.
__global__ __launch_bounds__(256) void k_logits(
    const float* __restrict__ Wo, const float* __restrict__ bo,
    const float* __restrict__ src, float* __restrict__ ws, int* __restrict__ wsI,
    float* __restrict__ dout, int t) {
  __shared__ __align__(16) float st[8192];
  __shared__ float redv[256];
  __shared__ int   redi[256];
  int tid = threadIdx.x;
  int wave = __builtin_amdgcn_readfirstlane(tid >> 6);
  int lane = tid & 63;
  int row0 = blockIdx.x * 32;
  float acc[8] = {0.f, 0.f, 0.f, 0.f, 0.f, 0.f, 0.f, 0.f};
  const float* Wbase = Wo + (long)(row0 + wave * 8) * 1024;
  for (int kt = 0; kt < 8; ++kt) {
    const float4* sp = (const float4*)(src + kt * 8192);
    float4* stp = (float4*)st;
    #pragma unroll
    for (int i = 0; i < 8; ++i) stp[tid + i * 256] = sp[tid + i * 256];
    __syncthreads();
    const float* Wt = Wbase + kt * 128;
    for (int k = 0; k < 128; k += 4) {
      float s0 = st[(k + 0) * 64 + lane], s1 = st[(k + 1) * 64 + lane];
      float s2 = st[(k + 2) * 64 + lane], s3 = st[(k + 3) * 64 + lane];
      #pragma unroll
      for (int jj = 0; jj < 8; ++jj) {
        float4 w = *(const float4*)(Wt + (long)jj * 1024 + k);
        acc[jj] = fmaf(w.w, s3, fmaf(w.z, s2, fmaf(w.y, s1, fmaf(w.x, s0, acc[jj]))));
      }
    }
    __syncthreads();
  }
  float bestv = -FLT_MAX; int besti = 0;
  long obase = (long)lane * (T_ * (long)V_) + (long)t * V_;
  #pragma unroll
  for (int jj = 0; jj < 8; ++jj) {
    int v = row0 + wave * 8 + jj;                 // ascending within wave
    float val = acc[jj] + bo[v];
    dout[obase + v] = val;
    if (val > bestv) { bestv = val; besti = v; }  // strict > keeps first on ties
  }
  redv[wave * 64 + lane] = bestv;
  redi[wave * 64 + lane] = besti;
  __syncthreads();
  if (tid < 64) {
    float bv = redv[tid]; int bi = redi[tid];
    #pragma unroll
    for (int w = 1; w < 4; ++w) {                 // ascending wave == ascending v
      float v2 = redv[w * 64 + tid];
      if (v2 > bv) { bv = v2; bi = redi[w * 64 + tid]; }
    }
    ws[PV_OFF + blockIdx.x * 64 + tid] = bv;
    wsI[PIDX_OFF + blockIdx.x * 64 + tid] = bi;
  }
}

__global__ void k_final(const float* __restrict__ ws, float* __restrict__ dout) {
  int n = blockIdx.x * 256 + threadIdx.x;         // 512 blocks -> 131072
  int k = n & 1023, b = (n >> 10) & 63, l = n >> 16;
  dout[OUT_H_OFF + (long)l * (B_ * H_) + (long)b * H_ + k] =
      ws[HT_OFF + l * 65536 + k * 64 + b];
}

extern "C" void kernel_launch(void* const* d_in, const int* in_sizes, int n_in,
                              void* d_out, int out_size, void* d_ws, size_t ws_size,
                              hipStream_t stream) {
  const float* enc_h = (const float*)d_in[1];
  const float* emb   = (const float*)d_in[2];
  const float* w_ih  = (const float*)d_in[3];
  const float* w_hh  = (const float*)d_in[4];
  const float* b_ih  = (const float*)d_in[5];
  const float* b_hh  = (const float*)d_in[6];
  const float* out_w = (const float*)d_in[7];
  const float* out_b = (const float*)d_in[8];
  float* ws  = (float*)d_ws;
  int*   wsI = (int*)d_ws;
  float* out = (float*)d_out;

  k_init<<<512, 256, 0, stream>>>(enc_h, ws, wsI);
  for (int t = 0; t < T_; ++t) {
    k_argmax_embed<<<1, 1024, 0, stream>>>(emb, ws, wsI, t > 0);
    for (int l = 0; l < 2; ++l) {
      const float* sx = (l == 0) ? (ws + XT_OFF) : (ws + HT_OFF);  // layer1 input = hT0
      float* hT = ws + HT_OFF + l * 65536;
      k_gemv_gru<<<384, 256, 0, stream>>>(w_ih + (long)l * R3H * 1024,
                                          w_hh + (long)l * R3H * 1024,
                                          b_ih + l * R3H, b_hh + l * R3H,
                                          sx, hT, ws + G_OFF);
      k_gates<<<256, 256, 0, stream>>>(ws + G_OFF, hT);
    }
    k_logits<<<1000, 256, 0, stream>>>(out_w, out_b, ws + HT_OFF + 65536,
                                       ws, wsI, out, t);
  }
  k_final<<<512, 256, 0, stream>>>(ws, out);
}

// Round 3
// 9250.318 us; speedup vs baseline: 2.0065x; 1.2115x over previous
//
#include <hip/hip_runtime.h>
#include <math.h>
#include <float.h>

// Decoder: 32-step greedy GRU decode. B=64, H=E=1024, L=2, V=32000, T=32.
// fp32. State layout: transposed [k][64] so lane=batch.
// R2: wave-parallel argmax finalize (303us -> ~10us).
// R3: LDS-staged weights (coalesced 1KB/instr loads) in k_logits/k_gemv_gru;
//     compute reads W via free LDS broadcast. FMA order unchanged vs R2.

#define B_ 64
#define H_ 1024
#define V_ 32000
#define T_ 32
#define R3H 3072

// workspace offsets (in 4-byte elements)
#define XT_OFF   0         // xT [1024][64]
#define HT_OFF   65536     // hT [2][1024][64]
#define G_OFF    196608    // gbuf [6144][64]
#define PV_OFF   589824    // pval [1000][64]
#define PIDX_OFF 653824    // pidx [1000][64] (int)
#define TOK_OFF  717824    // tok [64] (int)

#define OUT_H_OFF 65536000L  // 64*32*32000

__global__ void k_init(const float* __restrict__ enc_h, float* __restrict__ ws,
                       int* __restrict__ wsI) {
  int n = blockIdx.x * 256 + threadIdx.x;         // 512 blocks -> 131072 = 2*1024*64
  int b = n & 63, k = (n >> 6) & 1023, l = n >> 16;
  ws[HT_OFF + l * 65536 + k * 64 + b] = enc_h[l * (B_ * H_) + b * H_ + k];
  if (n < B_) wsI[TOK_OFF + n] = 0;               // START token
}

// Finalize argmax of previous step (1000 block-partials), then gather+relu embedding.
__global__ void k_argmax_embed(const float* __restrict__ emb, float* __restrict__ ws,
                               int* __restrict__ wsI, int do_argmax) {
  __shared__ float sv[1024];
  __shared__ int   si[1024];
  int tid = threadIdx.x;                          // 1024 threads, 1 block
  if (do_argmax) {
    int b = tid & 63, c = tid >> 6;               // chunk c in [0,16)
    float best = -FLT_MAX; int bi = 0x7fffffff;
    for (int i = c; i < 1000; i += 16) {
      float v  = ws[PV_OFF + i * 64 + b];
      int   ix = wsI[PIDX_OFF + i * 64 + b];
      if (v > best || (v == best && ix < bi)) { best = v; bi = ix; }
    }
    sv[c * 64 + b] = best;
    si[c * 64 + b] = bi;
    __syncthreads();
    if (tid < 64) {
      float bv = sv[tid]; int bix = si[tid];
      #pragma unroll
      for (int c2 = 1; c2 < 16; ++c2) {
        float v2 = sv[c2 * 64 + tid]; int i2 = si[c2 * 64 + tid];
        if (v2 > bv || (v2 == bv && i2 < bix)) { bv = v2; bix = i2; }
      }
      wsI[TOK_OFF + tid] = bix;                   // jnp.argmax: lowest index on ties
    }
  }
  __syncthreads();
  int b = tid >> 4, tl = tid & 15;
  const float* erow = emb + (long)wsI[TOK_OFF + b] * H_;
  #pragma unroll
  for (int c = 0; c < 16; ++c) {
    int e = c * 64 + tl * 4;
    float4 v = *(const float4*)(erow + e);
    ws[XT_OFF + (e + 0) * 64 + b] = fmaxf(v.x, 0.f);
    ws[XT_OFF + (e + 1) * 64 + b] = fmaxf(v.y, 0.f);
    ws[XT_OFF + (e + 2) * 64 + b] = fmaxf(v.z, 0.f);
    ws[XT_OFF + (e + 3) * 64 + b] = fmaxf(v.w, 0.f);
  }
}

// GRU gate gemms: rows 0..3071 = W_ih . xT (+b_ih), rows 3072..6143 = W_hh . hT (+b_hh).
// 16 rows/block (4 waves x 4 rows), K in 8 LDS-staged tiles of 128. W staged via LDS.
__global__ __launch_bounds__(256) void k_gemv_gru(
    const float* __restrict__ w_ih, const float* __restrict__ w_hh,
    const float* __restrict__ b_ih, const float* __restrict__ b_hh,
    const float* __restrict__ srcx, const float* __restrict__ srch,
    float* __restrict__ g) {
  __shared__ __align__(16) float st[8192];        // x tile [128 k][64 b]
  __shared__ __align__(16) float sw[2048];        // w tile [16 r][128 k]
  int tid = threadIdx.x;
  int wave = __builtin_amdgcn_readfirstlane(tid >> 6);
  int lane = tid & 63;
  int row0 = blockIdx.x * 16;
  bool use_x = row0 < R3H;
  const float* W    = use_x ? (w_ih + (long)row0 * 1024) : (w_hh + (long)(row0 - R3H) * 1024);
  const float* src  = use_x ? srcx : srch;
  const float* bias = use_x ? (b_ih + row0) : (b_hh + row0 - R3H);
  float acc[4] = {0.f, 0.f, 0.f, 0.f};
  for (int kt = 0; kt < 8; ++kt) {
    const float4* sp = (const float4*)(src + kt * 8192);
    float4* stp = (float4*)st;
    #pragma unroll
    for (int i = 0; i < 8; ++i) stp[tid + i * 256] = sp[tid + i * 256];
    #pragma unroll
    for (int i = 0; i < 2; ++i) {                 // coalesced W stage: 16 rows x 128 k
      int idx = i * 256 + tid;
      int r = idx >> 5, c = (idx & 31) << 2;
      *(float4*)&sw[r * 128 + c] = *(const float4*)(W + (long)r * 1024 + kt * 128 + c);
    }
    __syncthreads();
    for (int k = 0; k < 128; k += 4) {
      float s0 = st[(k + 0) * 64 + lane], s1 = st[(k + 1) * 64 + lane];
      float s2 = st[(k + 2) * 64 + lane], s3 = st[(k + 3) * 64 + lane];
      #pragma unroll
      for (int jj = 0; jj < 4; ++jj) {
        float4 w = *(const float4*)&sw[(wave * 4 + jj) * 128 + k];  // LDS broadcast
        acc[jj] = fmaf(w.w, s3, fmaf(w.z, s2, fmaf(w.y, s1, fmaf(w.x, s0, acc[jj]))));
      }
    }
    __syncthreads();
  }
  #pragma unroll
  for (int jj = 0; jj < 4; ++jj) {
    int r = wave * 4 + jj;
    g[(long)(row0 + r) * 64 + lane] = acc[jj] + bias[r];
  }
}

// Pointwise GRU gate math; updates hT[l] in place (torch gate order r,z,n).
__global__ void k_gates(const float* __restrict__ g, float* __restrict__ hT) {
  int n = blockIdx.x * 256 + threadIdx.x;         // 256 blocks -> 65536 = 1024*64
  int b = n & 63, j = n >> 6;
  float ir = g[(long)j * 64 + b];
  float iz = g[(long)(j + 1024) * 64 + b];
  float in = g[(long)(j + 2048) * 64 + b];
  float hr = g[(long)(3072 + j) * 64 + b];
  float hz = g[(long)(4096 + j) * 64 + b];
  float hn = g[(long)(5120 + j) * 64 + b];
  float r = 1.f / (1.f + expf(-(ir + hr)));
  float z = 1.f / (1.f + expf(-(iz + hz)));
  float nn = tanhf(in + r * hn);
  float ho = hT[(long)j * 64 + b];
  hT[(long)j * 64 + b] = (1.f - z) * nn + z * ho;
}

// Logits gemv: 32 rows/block (4 waves x 8 rows) over V=32000 -> 1000 blocks.
// W staged via LDS (coalesced); writes logits to d_out[b][t][v] + argmax partials.
__global__ __launch_bounds__(256) void k_logits(
    const float* __restrict__ Wo, const float* __restrict__ bo,
    const float* __restrict__ src, float* __restrict__ ws, int* __restrict__ wsI,
    float* __restrict__ dout, int t) {
  __shared__ __align__(16) float st[8192];        // x tile [128 k][64 b]
  __shared__ __align__(16) float sw[4096];        // w tile [32 r][128 k]
  __shared__ float redv[256];
  __shared__ int   redi[256];
  int tid = threadIdx.x;
  int wave = __builtin_amdgcn_readfirstlane(tid >> 6);
  int lane = tid & 63;
  int row0 = blockIdx.x * 32;
  float acc[8] = {0.f, 0.f, 0.f, 0.f, 0.f, 0.f, 0.f, 0.f};
  const float* W = Wo + (long)row0 * 1024;
  for (int kt = 0; kt < 8; ++kt) {
    const float4* sp = (const float4*)(src + kt * 8192);
    float4* stp = (float4*)st;
    #pragma unroll
    for (int i = 0; i < 8; ++i) stp[tid + i * 256] = sp[tid + i * 256];
    #pragma unroll
    for (int i = 0; i < 4; ++i) {                 // coalesced W stage: 32 rows x 128 k
      int idx = i * 256 + tid;
      int r = idx >> 5, c = (idx & 31) << 2;
      *(float4*)&sw[r * 128 + c] = *(const float4*)(W + (long)r * 1024 + kt * 128 + c);
    }
    __syncthreads();
    for (int k = 0; k < 128; k += 4) {
      float s0 = st[(k + 0) * 64 + lane], s1 = st[(k + 1) * 64 + lane];
      float s2 = st[(k + 2) * 64 + lane], s3 = st[(k + 3) * 64 + lane];
      #pragma unroll
      for (int jj = 0; jj < 8; ++jj) {
        float4 w = *(const float4*)&sw[(wave * 8 + jj) * 128 + k];  // LDS broadcast
        acc[jj] = fmaf(w.w, s3, fmaf(w.z, s2, fmaf(w.y, s1, fmaf(w.x, s0, acc[jj]))));
      }
    }
    __syncthreads();
  }
  float bestv = -FLT_MAX; int besti = 0;
  long obase = (long)lane * (T_ * (long)V_) + (long)t * V_;
  #pragma unroll
  for (int jj = 0; jj < 8; ++jj) {
    int v = row0 + wave * 8 + jj;                 // ascending within wave
    float val = acc[jj] + bo[v];
    dout[obase + v] = val;
    if (val > bestv) { bestv = val; besti = v; }  // strict > keeps first on ties
  }
  redv[wave * 64 + lane] = bestv;
  redi[wave * 64 + lane] = besti;
  __syncthreads();
  if (tid < 64) {
    float bv = redv[tid]; int bi = redi[tid];
    #pragma unroll
    for (int w = 1; w < 4; ++w) {                 // ascending wave == ascending v
      float v2 = redv[w * 64 + tid];
      if (v2 > bv) { bv = v2; bi = redi[w * 64 + tid]; }
    }
    ws[PV_OFF + blockIdx.x * 64 + tid] = bv;
    wsI[PIDX_OFF + blockIdx.x * 64 + tid] = bi;
  }
}

__global__ void k_final(const float* __restrict__ ws, float* __restrict__ dout) {
  int n = blockIdx.x * 256 + threadIdx.x;         // 512 blocks -> 131072
  int k = n & 1023, b = (n >> 10) & 63, l = n >> 16;
  dout[OUT_H_OFF + (long)l * (B_ * H_) + (long)b * H_ + k] =
      ws[HT_OFF + l * 65536 + k * 64 + b];
}

extern "C" void kernel_launch(void* const* d_in, const int* in_sizes, int n_in,
                              void* d_out, int out_size, void* d_ws, size_t ws_size,
                              hipStream_t stream) {
  const float* enc_h = (const float*)d_in[1];
  const float* emb   = (const float*)d_in[2];
  const float* w_ih  = (const float*)d_in[3];
  const float* w_hh  = (const float*)d_in[4];
  const float* b_ih  = (const float*)d_in[5];
  const float* b_hh  = (const float*)d_in[6];
  const float* out_w = (const float*)d_in[7];
  const float* out_b = (const float*)d_in[8];
  float* ws  = (float*)d_ws;
  int*   wsI = (int*)d_ws;
  float* out = (float*)d_out;

  k_init<<<512, 256, 0, stream>>>(enc_h, ws, wsI);
  for (int t = 0; t < T_; ++t) {
    k_argmax_embed<<<1, 1024, 0, stream>>>(emb, ws, wsI, t > 0);
    for (int l = 0; l < 2; ++l) {
      const float* sx = (l == 0) ? (ws + XT_OFF) : (ws + HT_OFF);  // layer1 input = hT0
      float* hT = ws + HT_OFF + l * 65536;
      k_gemv_gru<<<384, 256, 0, stream>>>(w_ih + (long)l * R3H * 1024,
                                          w_hh + (long)l * R3H * 1024,
                                          b_ih + l * R3H, b_hh + l * R3H,
                                          sx, hT, ws + G_OFF);
      k_gates<<<256, 256, 0, stream>>>(ws + G_OFF, hT);
    }
    k_logits<<<1000, 256, 0, stream>>>(out_w, out_b, ws + HT_OFF + 65536,
                                       ws, wsI, out, t);
  }
  k_final<<<512, 256, 0, stream>>>(ws, out);
}

// Round 4
// 5189.106 us; speedup vs baseline: 3.5768x; 1.7826x over previous
//
#include <hip/hip_runtime.h>
#include <math.h>
#include <float.h>

// Decoder: 32-step greedy GRU decode. B=64, H=E=1024, L=2, V=32000, T=32.
// R4: all GEMMs via mfma_f32_16x16x32_bf16 with bf16 hi/lo split (3 MFMA per
// tile: hihi+hilo+lohi ~ fp32 precision). No LDS: A-frags from HBM (64B
// segments), B-frags from L2-resident state. 1-wave blocks, 32 rows x 64 batch.

#define B_ 64
#define H_ 1024
#define V_ 32000
#define T_ 32

typedef unsigned short u16;
typedef float f32x4 __attribute__((ext_vector_type(4)));
typedef short s16x8 __attribute__((ext_vector_type(8)));
#define MFMA16 __builtin_amdgcn_mfma_f32_16x16x32_bf16

// workspace byte offsets (all 256-aligned)
#define WOH_B   0UL           // out_w hi bf16 [32000][1024]  (65,536,000 B)
#define WOL_B   65536000UL    // out_w lo
#define WIHH_B  131072000UL   // w_ih hi [2][3072][1024] (12,582,912 B)
#define WIHL_B  143654912UL
#define WHHH_B  156237824UL   // w_hh hi
#define WHHL_B  168820736UL
#define XH_B    181403648UL   // x hi bf16 [64][1024] (131,072 B)
#define XL_B    181534720UL
#define HBH_B   181665792UL   // h hi bf16 [2][64][1024] (262,144 B)
#define HBL_B   181927936UL
#define HF_B    182190080UL   // h f32 [2][64][1024] (524,288 B)
#define GT_B    182714368UL   // g_t f32 [64][6144] (1,572,864 B)
#define PV_B    184287232UL   // pval [1000][64] f32
#define PI_B    184543232UL   // pidx [1000][64] i32
#define TK_B    184799232UL   // tok [64] i32

#define OUT_H_OFF 65536000L   // 64*32*32000

__device__ __forceinline__ void bf16split(float x, u16& h, u16& l) {
  unsigned u = __float_as_uint(x);
  unsigned r = u + 0x7fff + ((u >> 16) & 1);          // RTN to bf16
  h = (u16)(r >> 16);
  float hf = __uint_as_float((unsigned)h << 16);
  float rem = x - hf;                                  // exact (Sterbenz)
  unsigned u2 = __float_as_uint(rem);
  unsigned r2 = u2 + 0x7fff + ((u2 >> 16) & 1);
  l = (u16)(r2 >> 16);
}

// fp32 -> (hi,lo) bf16 arrays, grid-stride over float4s.
__global__ void k_convert(const float* __restrict__ src, u16* __restrict__ hi,
                          u16* __restrict__ lo, int n4) {
  int i = blockIdx.x * 256 + threadIdx.x;
  int stride = gridDim.x * 256;
  for (; i < n4; i += stride) {
    float4 v = ((const float4*)src)[i];
    float x[4] = {v.x, v.y, v.z, v.w};
    u16 hh[4], ll[4];
    #pragma unroll
    for (int j = 0; j < 4; ++j) bf16split(x[j], hh[j], ll[j]);
    ushort4 ho; ho.x = hh[0]; ho.y = hh[1]; ho.z = hh[2]; ho.w = hh[3];
    ushort4 lv; lv.x = ll[0]; lv.y = ll[1]; lv.z = ll[2]; lv.w = ll[3];
    ((ushort4*)hi)[i] = ho;
    ((ushort4*)lo)[i] = lv;
  }
}

__global__ void k_init(const float* __restrict__ enc_h, float* __restrict__ hf,
                       u16* __restrict__ hhi, u16* __restrict__ hlo,
                       int* __restrict__ tok) {
  int n = blockIdx.x * 256 + threadIdx.x;   // 512*256 = 131072 = 2*64*1024
  float v = enc_h[n];                       // [l][b][k] layout matches
  hf[n] = v;
  u16 h, l; bf16split(v, h, l);
  hhi[n] = h; hlo[n] = l;
  if (n < B_) tok[n] = 0;                   // START token
}

// Finalize argmax partials, gather+relu embedding, emit x bf16 hi/lo [b][k].
__global__ void k_argmax_embed(const float* __restrict__ emb,
                               const float* __restrict__ pv, const int* __restrict__ pidx,
                               int* __restrict__ tok, u16* __restrict__ xhi,
                               u16* __restrict__ xlo, int do_argmax) {
  __shared__ float sv[1024];
  __shared__ int   si[1024];
  int tid = threadIdx.x;                    // 1024 threads, 1 block
  if (do_argmax) {
    int b = tid & 63, c = tid >> 6;
    float best = -FLT_MAX; int bi = 0x7fffffff;
    for (int i = c; i < 1000; i += 16) {
      float v = pv[i * 64 + b];
      int  ix = pidx[i * 64 + b];
      if (v > best || (v == best && ix < bi)) { best = v; bi = ix; }
    }
    sv[c * 64 + b] = best; si[c * 64 + b] = bi;
    __syncthreads();
    if (tid < 64) {
      float bv = sv[tid]; int bix = si[tid];
      #pragma unroll
      for (int c2 = 1; c2 < 16; ++c2) {
        float v2 = sv[c2 * 64 + tid]; int i2 = si[c2 * 64 + tid];
        if (v2 > bv || (v2 == bv && i2 < bix)) { bv = v2; bix = i2; }
      }
      tok[tid] = bix;                       // jnp.argmax: lowest index on ties
    }
  }
  __syncthreads();
  int b = tid >> 4, tl = tid & 15;
  const float* erow = emb + (long)tok[b] * H_;
  #pragma unroll
  for (int c = 0; c < 16; ++c) {
    int e = c * 64 + tl * 4;
    float4 v = *(const float4*)(erow + e);
    float x0 = fmaxf(v.x, 0.f), x1 = fmaxf(v.y, 0.f);
    float x2 = fmaxf(v.z, 0.f), x3 = fmaxf(v.w, 0.f);
    u16 h0,h1,h2,h3,l0,l1,l2,l3;
    bf16split(x0,h0,l0); bf16split(x1,h1,l1); bf16split(x2,h2,l2); bf16split(x3,h3,l3);
    ushort4 hv; hv.x=h0; hv.y=h1; hv.z=h2; hv.w=h3;
    ushort4 lv; lv.x=l0; lv.y=l1; lv.z=l2; lv.w=l3;
    *(ushort4*)(xhi + b * 1024 + e) = hv;
    *(ushort4*)(xlo + b * 1024 + e) = lv;
  }
}

// Core: one wave computes D[32 rows][64 batch] = A(32x1024) . B^T(64x1024)^T
// via bf16x3. A, B row-major K-inner bf16 hi/lo. Frag layout (16x16x32):
// A: lane holds A[lane&15][(lane>>4)*8 + j]; B: B^T[lane&15][(lane>>4)*8 + j];
// D: D[(lane>>4)*4 + r][lane&15].
__device__ __forceinline__ void gemm32x64(
    const u16* __restrict__ Ahi, const u16* __restrict__ Alo,
    const u16* __restrict__ Bhi, const u16* __restrict__ Blo,
    int lane, f32x4 (&acc)[2][4]) {
  int l15 = lane & 15, l4 = lane >> 4;
  const u16* pah = Ahi + l15 * 1024 + l4 * 8;
  const u16* pal = Alo + l15 * 1024 + l4 * 8;
  const u16* pbh = Bhi + l15 * 1024 + l4 * 8;
  const u16* pbl = Blo + l15 * 1024 + l4 * 8;
  #pragma unroll 2
  for (int k0 = 0; k0 < 1024; k0 += 32) {
    s16x8 ah0 = *(const s16x8*)(pah + k0);
    s16x8 ah1 = *(const s16x8*)(pah + 16 * 1024 + k0);
    s16x8 al0 = *(const s16x8*)(pal + k0);
    s16x8 al1 = *(const s16x8*)(pal + 16 * 1024 + k0);
    #pragma unroll
    for (int nt = 0; nt < 4; ++nt) {
      s16x8 bh = *(const s16x8*)(pbh + nt * 16 * 1024 + k0);
      s16x8 bl = *(const s16x8*)(pbl + nt * 16 * 1024 + k0);
      acc[0][nt] = MFMA16(ah0, bh, acc[0][nt], 0, 0, 0);
      acc[1][nt] = MFMA16(ah1, bh, acc[1][nt], 0, 0, 0);
      acc[0][nt] = MFMA16(ah0, bl, acc[0][nt], 0, 0, 0);
      acc[1][nt] = MFMA16(ah1, bl, acc[1][nt], 0, 0, 0);
      acc[0][nt] = MFMA16(al0, bh, acc[0][nt], 0, 0, 0);
      acc[1][nt] = MFMA16(al1, bh, acc[1][nt], 0, 0, 0);
    }
  }
}

// GRU gate GEMM: blocks 0..95 -> W_ih rows (vs layer input x), 96..191 -> W_hh
// rows (vs h state). Writes g_t[b][row(+3072 for hh)] with bias added.
__global__ __launch_bounds__(64) void k_gru(
    const u16* __restrict__ aih_hi, const u16* __restrict__ aih_lo,
    const u16* __restrict__ ahh_hi, const u16* __restrict__ ahh_lo,
    const float* __restrict__ bih, const float* __restrict__ bhh,
    const u16* __restrict__ xb_hi, const u16* __restrict__ xb_lo,
    const u16* __restrict__ hb_hi, const u16* __restrict__ hb_lo,
    float* __restrict__ gt) {
  int lane = threadIdx.x;
  int l15 = lane & 15, l4 = lane >> 4;
  int blk = blockIdx.x;
  bool ih = blk < 96;
  int row0 = (ih ? blk : blk - 96) * 32;
  const u16* Ahi = (ih ? aih_hi : ahh_hi) + (size_t)row0 * 1024;
  const u16* Alo = (ih ? aih_lo : ahh_lo) + (size_t)row0 * 1024;
  const u16* Bhi = ih ? xb_hi : hb_hi;
  const u16* Blo = ih ? xb_lo : hb_lo;
  const float* bias = (ih ? bih : bhh) + row0;
  f32x4 acc[2][4];
  #pragma unroll
  for (int m = 0; m < 2; ++m)
    #pragma unroll
    for (int n = 0; n < 4; ++n) acc[m][n] = (f32x4){0.f, 0.f, 0.f, 0.f};
  gemm32x64(Ahi, Alo, Bhi, Blo, lane, acc);
  int grow0 = (ih ? 0 : 3072) + row0;
  #pragma unroll
  for (int mt = 0; mt < 2; ++mt) {
    f32x4 bs = *(const f32x4*)(bias + mt * 16 + l4 * 4);
    #pragma unroll
    for (int nt = 0; nt < 4; ++nt) {
      f32x4 v = acc[mt][nt] + bs;
      int b = nt * 16 + l15;
      *(f32x4*)(gt + (size_t)b * 6144 + grow0 + mt * 16 + l4 * 4) = v;
    }
  }
}

// Pointwise GRU gates (torch order r,z,n); updates h f32 + bf16 hi/lo.
__global__ void k_gates(const float* __restrict__ gt, float* __restrict__ hf,
                        u16* __restrict__ hhi, u16* __restrict__ hlo) {
  int n = blockIdx.x * 256 + threadIdx.x;   // 65536 = 64*1024, [b][j]
  int b = n >> 10, j = n & 1023;
  const float* gb = gt + (size_t)b * 6144;
  float ir = gb[j], iz = gb[j + 1024], inn = gb[j + 2048];
  float hr = gb[j + 3072], hz = gb[j + 4096], hn = gb[j + 5120];
  float r = 1.f / (1.f + expf(-(ir + hr)));
  float z = 1.f / (1.f + expf(-(iz + hz)));
  float nn = tanhf(inn + r * hn);
  float ho = hf[n];
  float hv = (1.f - z) * nn + z * ho;
  hf[n] = hv;
  u16 hh, ll; bf16split(hv, hh, ll);
  hhi[n] = hh; hlo[n] = ll;
}

// Logits: 1000 blocks x 1 wave, 32 vocab rows x 64 batch each.
// Writes logits (nontemporal) + per-block argmax partials.
__global__ __launch_bounds__(64) void k_logits(
    const u16* __restrict__ whi, const u16* __restrict__ wlo,
    const float* __restrict__ bo, const u16* __restrict__ xhi,
    const u16* __restrict__ xlo, float* __restrict__ pv, int* __restrict__ pidx,
    float* __restrict__ dout, int t) {
  int lane = threadIdx.x;
  int l15 = lane & 15, l4 = lane >> 4;
  int v0 = blockIdx.x * 32;
  f32x4 acc[2][4];
  #pragma unroll
  for (int m = 0; m < 2; ++m)
    #pragma unroll
    for (int n = 0; n < 4; ++n) acc[m][n] = (f32x4){0.f, 0.f, 0.f, 0.f};
  gemm32x64(whi + (size_t)v0 * 1024, wlo + (size_t)v0 * 1024, xhi, xlo, lane, acc);
  f32x4 out[2][4];
  #pragma unroll
  for (int mt = 0; mt < 2; ++mt) {
    f32x4 bs = *(const f32x4*)(bo + v0 + mt * 16 + l4 * 4);
    #pragma unroll
    for (int nt = 0; nt < 4; ++nt) {
      out[mt][nt] = acc[mt][nt] + bs;
      long b = nt * 16 + l15;
      float* addr = dout + b * (T_ * (long)V_) + (long)t * V_ + v0 + mt * 16 + l4 * 4;
      __builtin_nontemporal_store(out[mt][nt], (f32x4*)addr);
    }
  }
  // argmax: per N-tile reduce over (mt, reg) then across l4 groups via shfl.
  float bvv0, bvv1, bvv2, bvv3; int bii0, bii1, bii2, bii3;
  #pragma unroll
  for (int nt = 0; nt < 4; ++nt) {
    float bv = -FLT_MAX; int bi = 0;
    #pragma unroll
    for (int mt = 0; mt < 2; ++mt)
      #pragma unroll
      for (int r = 0; r < 4; ++r) {
        float v = out[mt][nt][r];
        if (v > bv) { bv = v; bi = v0 + mt * 16 + l4 * 4 + r; }  // ascending idx
      }
    #pragma unroll
    for (int off = 16; off < 64; off <<= 1) {
      float ov = __shfl_xor(bv, off, 64);
      int   oi = __shfl_xor(bi, off, 64);
      if (ov > bv || (ov == bv && oi < bi)) { bv = ov; bi = oi; }
    }
    if (nt == 0) { bvv0 = bv; bii0 = bi; }
    else if (nt == 1) { bvv1 = bv; bii1 = bi; }
    else if (nt == 2) { bvv2 = bv; bii2 = bi; }
    else { bvv3 = bv; bii3 = bi; }
  }
  float fb = bvv0; int fi = bii0;
  if (l4 == 1) { fb = bvv1; fi = bii1; }
  else if (l4 == 2) { fb = bvv2; fi = bii2; }
  else if (l4 == 3) { fb = bvv3; fi = bii3; }
  pv[blockIdx.x * 64 + lane] = fb;     // lane == batch b = l4*16 + l15
  pidx[blockIdx.x * 64 + lane] = fi;
}

__global__ void k_final(const float* __restrict__ hf, float* __restrict__ dout) {
  int n = blockIdx.x * 256 + threadIdx.x;   // 131072; hf layout == out layout
  dout[OUT_H_OFF + n] = hf[n];
}

extern "C" void kernel_launch(void* const* d_in, const int* in_sizes, int n_in,
                              void* d_out, int out_size, void* d_ws, size_t ws_size,
                              hipStream_t stream) {
  const float* enc_h = (const float*)d_in[1];
  const float* emb   = (const float*)d_in[2];
  const float* w_ih  = (const float*)d_in[3];
  const float* w_hh  = (const float*)d_in[4];
  const float* b_ih  = (const float*)d_in[5];
  const float* b_hh  = (const float*)d_in[6];
  const float* out_w = (const float*)d_in[7];
  const float* out_b = (const float*)d_in[8];
  float* out = (float*)d_out;
  char* wsb = (char*)d_ws;

  u16* woh  = (u16*)(wsb + WOH_B);
  u16* wol  = (u16*)(wsb + WOL_B);
  u16* wihh = (u16*)(wsb + WIHH_B);
  u16* wihl = (u16*)(wsb + WIHL_B);
  u16* whhh = (u16*)(wsb + WHHH_B);
  u16* whhl = (u16*)(wsb + WHHL_B);
  u16* xh   = (u16*)(wsb + XH_B);
  u16* xl   = (u16*)(wsb + XL_B);
  u16* hbh  = (u16*)(wsb + HBH_B);
  u16* hbl  = (u16*)(wsb + HBL_B);
  float* hf = (float*)(wsb + HF_B);
  float* gt = (float*)(wsb + GT_B);
  float* pv = (float*)(wsb + PV_B);
  int* pidx = (int*)(wsb + PI_B);
  int* tok  = (int*)(wsb + TK_B);

  k_convert<<<4096, 256, 0, stream>>>(out_w, woh, wol, 8192000);
  k_convert<<<2048, 256, 0, stream>>>(w_ih, wihh, wihl, 1572864);
  k_convert<<<2048, 256, 0, stream>>>(w_hh, whhh, whhl, 1572864);
  k_init<<<512, 256, 0, stream>>>(enc_h, hf, hbh, hbl, tok);

  for (int t = 0; t < T_; ++t) {
    k_argmax_embed<<<1, 1024, 0, stream>>>(emb, pv, pidx, tok, xh, xl, t > 0);
    for (int l = 0; l < 2; ++l) {
      const u16* bxh = (l == 0) ? xh : hbh;   // layer 1 input = h[0]
      const u16* bxl = (l == 0) ? xl : hbl;
      k_gru<<<192, 64, 0, stream>>>(wihh + (size_t)l * 3145728, wihl + (size_t)l * 3145728,
                                    whhh + (size_t)l * 3145728, whhl + (size_t)l * 3145728,
                                    b_ih + l * 3072, b_hh + l * 3072,
                                    bxh, bxl, hbh + l * 65536, hbl + l * 65536, gt);
      k_gates<<<256, 256, 0, stream>>>(gt, hf + l * 65536, hbh + l * 65536, hbl + l * 65536);
    }
    k_logits<<<1000, 64, 0, stream>>>(woh, wol, out_b, hbh + 65536, hbl + 65536,
                                      pv, pidx, out, t);
  }
  k_final<<<512, 256, 0, stream>>>(hf, out);
}

// Round 5
// 3780.481 us; speedup vs baseline: 4.9095x; 1.3726x over previous
//
#include <hip/hip_runtime.h>
#include <math.h>
#include <float.h>

// Decoder: 32-step greedy GRU decode. B=64, H=E=1024, L=2, V=32000, T=32.
// R4: all GEMMs via mfma_f32_16x16x32_bf16, bf16 hi/lo split (hihi+hilo+lohi).
// R5: 4-wave blocks splitting K=1024 into 4x256 slices + LDS reduce.
//     Fixes 1-wave/SIMD latency-bound GEMMs (occupancy 2.4% -> ~15%).

#define B_ 64
#define H_ 1024
#define V_ 32000
#define T_ 32

typedef unsigned short u16;
typedef float f32x4 __attribute__((ext_vector_type(4)));
typedef short s16x8 __attribute__((ext_vector_type(8)));
#define MFMA16 __builtin_amdgcn_mfma_f32_16x16x32_bf16

// workspace byte offsets (all 256-aligned)
#define WOH_B   0UL           // out_w hi bf16 [32000][1024]  (65,536,000 B)
#define WOL_B   65536000UL    // out_w lo
#define WIHH_B  131072000UL   // w_ih hi [2][3072][1024] (12,582,912 B)
#define WIHL_B  143654912UL
#define WHHH_B  156237824UL   // w_hh hi
#define WHHL_B  168820736UL
#define XH_B    181403648UL   // x hi bf16 [64][1024] (131,072 B)
#define XL_B    181534720UL
#define HBH_B   181665792UL   // h hi bf16 [2][64][1024] (262,144 B)
#define HBL_B   181927936UL
#define HF_B    182190080UL   // h f32 [2][64][1024] (524,288 B)
#define GT_B    182714368UL   // g_t f32 [64][6144] (1,572,864 B)
#define PV_B    184287232UL   // pval [1000][64] f32
#define PI_B    184543232UL   // pidx [1000][64] i32
#define TK_B    184799232UL   // tok [64] i32

#define OUT_H_OFF 65536000L   // 64*32*32000

__device__ __forceinline__ void bf16split(float x, u16& h, u16& l) {
  unsigned u = __float_as_uint(x);
  unsigned r = u + 0x7fff + ((u >> 16) & 1);          // RTN to bf16
  h = (u16)(r >> 16);
  float hf = __uint_as_float((unsigned)h << 16);
  float rem = x - hf;                                  // exact (Sterbenz)
  unsigned u2 = __float_as_uint(rem);
  unsigned r2 = u2 + 0x7fff + ((u2 >> 16) & 1);
  l = (u16)(r2 >> 16);
}

// fp32 -> (hi,lo) bf16 arrays, grid-stride over float4s.
__global__ void k_convert(const float* __restrict__ src, u16* __restrict__ hi,
                          u16* __restrict__ lo, int n4) {
  int i = blockIdx.x * 256 + threadIdx.x;
  int stride = gridDim.x * 256;
  for (; i < n4; i += stride) {
    float4 v = ((const float4*)src)[i];
    float x[4] = {v.x, v.y, v.z, v.w};
    u16 hh[4], ll[4];
    #pragma unroll
    for (int j = 0; j < 4; ++j) bf16split(x[j], hh[j], ll[j]);
    ushort4 ho; ho.x = hh[0]; ho.y = hh[1]; ho.z = hh[2]; ho.w = hh[3];
    ushort4 lv; lv.x = ll[0]; lv.y = ll[1]; lv.z = ll[2]; lv.w = ll[3];
    ((ushort4*)hi)[i] = ho;
    ((ushort4*)lo)[i] = lv;
  }
}

__global__ void k_init(const float* __restrict__ enc_h, float* __restrict__ hf,
                       u16* __restrict__ hhi, u16* __restrict__ hlo,
                       int* __restrict__ tok) {
  int n = blockIdx.x * 256 + threadIdx.x;   // 512*256 = 131072 = 2*64*1024
  float v = enc_h[n];                       // [l][b][k] layout matches
  hf[n] = v;
  u16 h, l; bf16split(v, h, l);
  hhi[n] = h; hlo[n] = l;
  if (n < B_) tok[n] = 0;                   // START token
}

// Finalize argmax partials, gather+relu embedding, emit x bf16 hi/lo [b][k].
__global__ void k_argmax_embed(const float* __restrict__ emb,
                               const float* __restrict__ pv, const int* __restrict__ pidx,
                               int* __restrict__ tok, u16* __restrict__ xhi,
                               u16* __restrict__ xlo, int do_argmax) {
  __shared__ float sv[1024];
  __shared__ int   si[1024];
  int tid = threadIdx.x;                    // 1024 threads, 1 block
  if (do_argmax) {
    int b = tid & 63, c = tid >> 6;
    float best = -FLT_MAX; int bi = 0x7fffffff;
    for (int i = c; i < 1000; i += 16) {
      float v = pv[i * 64 + b];
      int  ix = pidx[i * 64 + b];
      if (v > best || (v == best && ix < bi)) { best = v; bi = ix; }
    }
    sv[c * 64 + b] = best; si[c * 64 + b] = bi;
    __syncthreads();
    if (tid < 64) {
      float bv = sv[tid]; int bix = si[tid];
      #pragma unroll
      for (int c2 = 1; c2 < 16; ++c2) {
        float v2 = sv[c2 * 64 + tid]; int i2 = si[c2 * 64 + tid];
        if (v2 > bv || (v2 == bv && i2 < bix)) { bv = v2; bix = i2; }
      }
      tok[tid] = bix;                       // jnp.argmax: lowest index on ties
    }
  }
  __syncthreads();
  int b = tid >> 4, tl = tid & 15;
  const float* erow = emb + (long)tok[b] * H_;
  #pragma unroll
  for (int c = 0; c < 16; ++c) {
    int e = c * 64 + tl * 4;
    float4 v = *(const float4*)(erow + e);
    float x0 = fmaxf(v.x, 0.f), x1 = fmaxf(v.y, 0.f);
    float x2 = fmaxf(v.z, 0.f), x3 = fmaxf(v.w, 0.f);
    u16 h0,h1,h2,h3,l0,l1,l2,l3;
    bf16split(x0,h0,l0); bf16split(x1,h1,l1); bf16split(x2,h2,l2); bf16split(x3,h3,l3);
    ushort4 hv; hv.x=h0; hv.y=h1; hv.z=h2; hv.w=h3;
    ushort4 lv; lv.x=l0; lv.y=l1; lv.z=l2; lv.w=l3;
    *(ushort4*)(xhi + b * 1024 + e) = hv;
    *(ushort4*)(xlo + b * 1024 + e) = lv;
  }
}

// One wave computes a K-slice (256 of 1024) of D[32 rows][64 batch] =
// A(32xK) . B^T(64xK)^T via bf16x3. Frag layout (16x16x32, verified R4):
// A: lane holds A[lane&15][(lane>>4)*8 + j]; B: B^T[lane&15][(lane>>4)*8 + j];
// D: D[(lane>>4)*4 + r][lane&15].
__device__ __forceinline__ void gemm32x64_slice(
    const u16* __restrict__ Ahi, const u16* __restrict__ Alo,
    const u16* __restrict__ Bhi, const u16* __restrict__ Blo,
    int lane, int kbeg, f32x4 (&acc)[2][4]) {
  int l15 = lane & 15, l4 = lane >> 4;
  const u16* pah = Ahi + l15 * 1024 + l4 * 8 + kbeg;
  const u16* pal = Alo + l15 * 1024 + l4 * 8 + kbeg;
  const u16* pbh = Bhi + l15 * 1024 + l4 * 8 + kbeg;
  const u16* pbl = Blo + l15 * 1024 + l4 * 8 + kbeg;
  #pragma unroll 2
  for (int k0 = 0; k0 < 256; k0 += 32) {
    s16x8 ah0 = *(const s16x8*)(pah + k0);
    s16x8 ah1 = *(const s16x8*)(pah + 16 * 1024 + k0);
    s16x8 al0 = *(const s16x8*)(pal + k0);
    s16x8 al1 = *(const s16x8*)(pal + 16 * 1024 + k0);
    #pragma unroll
    for (int nt = 0; nt < 4; ++nt) {
      s16x8 bh = *(const s16x8*)(pbh + nt * 16 * 1024 + k0);
      s16x8 bl = *(const s16x8*)(pbl + nt * 16 * 1024 + k0);
      acc[0][nt] = MFMA16(ah0, bh, acc[0][nt], 0, 0, 0);
      acc[1][nt] = MFMA16(ah1, bh, acc[1][nt], 0, 0, 0);
      acc[0][nt] = MFMA16(ah0, bl, acc[0][nt], 0, 0, 0);
      acc[1][nt] = MFMA16(ah1, bl, acc[1][nt], 0, 0, 0);
      acc[0][nt] = MFMA16(al0, bh, acc[0][nt], 0, 0, 0);
      acc[1][nt] = MFMA16(al1, bh, acc[1][nt], 0, 0, 0);
    }
  }
}

// GRU gate GEMM: blocks 0..95 -> W_ih rows (vs layer input x), 96..191 -> W_hh
// rows (vs h state). 4 waves split K; LDS reduce; writes g_t[b][row] + bias.
__global__ __launch_bounds__(256) void k_gru(
    const u16* __restrict__ aih_hi, const u16* __restrict__ aih_lo,
    const u16* __restrict__ ahh_hi, const u16* __restrict__ ahh_lo,
    const float* __restrict__ bih, const float* __restrict__ bhh,
    const u16* __restrict__ xb_hi, const u16* __restrict__ xb_lo,
    const u16* __restrict__ hb_hi, const u16* __restrict__ hb_lo,
    float* __restrict__ gt) {
  __shared__ f32x4 sacc[4][64][9];          // [wave][lane][mt*4+nt], pad->9
  int tid = threadIdx.x;
  int wave = tid >> 6, lane = tid & 63;
  int l15 = lane & 15, l4 = lane >> 4;
  int blk = blockIdx.x;
  bool ih = blk < 96;
  int row0 = (ih ? blk : blk - 96) * 32;
  const u16* Ahi = (ih ? aih_hi : ahh_hi) + (size_t)row0 * 1024;
  const u16* Alo = (ih ? aih_lo : ahh_lo) + (size_t)row0 * 1024;
  const u16* Bhi = ih ? xb_hi : hb_hi;
  const u16* Blo = ih ? xb_lo : hb_lo;
  const float* bias = (ih ? bih : bhh) + row0;
  f32x4 acc[2][4];
  #pragma unroll
  for (int m = 0; m < 2; ++m)
    #pragma unroll
    for (int n = 0; n < 4; ++n) acc[m][n] = (f32x4){0.f, 0.f, 0.f, 0.f};
  gemm32x64_slice(Ahi, Alo, Bhi, Blo, lane, wave * 256, acc);
  #pragma unroll
  for (int mt = 0; mt < 2; ++mt)
    #pragma unroll
    for (int nt = 0; nt < 4; ++nt) sacc[wave][lane][mt * 4 + nt] = acc[mt][nt];
  __syncthreads();
  // wave w owns batch tile nt=w: reduce K-slices, add bias, store.
  int grow0 = (ih ? 0 : 3072) + row0;
  int b = wave * 16 + l15;
  #pragma unroll
  for (int mt = 0; mt < 2; ++mt) {
    f32x4 s = sacc[0][lane][mt * 4 + wave];
    #pragma unroll
    for (int j = 1; j < 4; ++j) s += sacc[j][lane][mt * 4 + wave];
    f32x4 bs = *(const f32x4*)(bias + mt * 16 + l4 * 4);
    *(f32x4*)(gt + (size_t)b * 6144 + grow0 + mt * 16 + l4 * 4) = s + bs;
  }
}

// Pointwise GRU gates (torch order r,z,n); updates h f32 + bf16 hi/lo.
__global__ void k_gates(const float* __restrict__ gt, float* __restrict__ hf,
                        u16* __restrict__ hhi, u16* __restrict__ hlo) {
  int n = blockIdx.x * 256 + threadIdx.x;   // 65536 = 64*1024, [b][j]
  int b = n >> 10, j = n & 1023;
  const float* gb = gt + (size_t)b * 6144;
  float ir = gb[j], iz = gb[j + 1024], inn = gb[j + 2048];
  float hr = gb[j + 3072], hz = gb[j + 4096], hn = gb[j + 5120];
  float r = 1.f / (1.f + expf(-(ir + hr)));
  float z = 1.f / (1.f + expf(-(iz + hz)));
  float nn = tanhf(inn + r * hn);
  float ho = hf[n];
  float hv = (1.f - z) * nn + z * ho;
  hf[n] = hv;
  u16 hh, ll; bf16split(hv, hh, ll);
  hhi[n] = hh; hlo[n] = ll;
}

// Logits: 1000 blocks x 4 waves; 32 vocab rows x 64 batch; waves split K.
// Writes logits (nontemporal) + per-block argmax partials.
__global__ __launch_bounds__(256) void k_logits(
    const u16* __restrict__ whi, const u16* __restrict__ wlo,
    const float* __restrict__ bo, const u16* __restrict__ xhi,
    const u16* __restrict__ xlo, float* __restrict__ pv, int* __restrict__ pidx,
    float* __restrict__ dout, int t) {
  __shared__ f32x4 sacc[4][64][9];          // [wave][lane][mt*4+nt], pad->9
  int tid = threadIdx.x;
  int wave = tid >> 6, lane = tid & 63;
  int l15 = lane & 15, l4 = lane >> 4;
  int v0 = blockIdx.x * 32;
  f32x4 acc[2][4];
  #pragma unroll
  for (int m = 0; m < 2; ++m)
    #pragma unroll
    for (int n = 0; n < 4; ++n) acc[m][n] = (f32x4){0.f, 0.f, 0.f, 0.f};
  gemm32x64_slice(whi + (size_t)v0 * 1024, wlo + (size_t)v0 * 1024,
                  xhi, xlo, lane, wave * 256, acc);
  #pragma unroll
  for (int mt = 0; mt < 2; ++mt)
    #pragma unroll
    for (int nt = 0; nt < 4; ++nt) sacc[wave][lane][mt * 4 + nt] = acc[mt][nt];
  __syncthreads();
  // wave w owns batch tile nt=w: reduce K-slices, add bias, store, argmax.
  long b = wave * 16 + l15;
  f32x4 out2[2];
  #pragma unroll
  for (int mt = 0; mt < 2; ++mt) {
    f32x4 s = sacc[0][lane][mt * 4 + wave];
    #pragma unroll
    for (int j = 1; j < 4; ++j) s += sacc[j][lane][mt * 4 + wave];
    f32x4 bs = *(const f32x4*)(bo + v0 + mt * 16 + l4 * 4);
    out2[mt] = s + bs;
    float* addr = dout + b * (T_ * (long)V_) + (long)t * V_ + v0 + mt * 16 + l4 * 4;
    __builtin_nontemporal_store(out2[mt], (f32x4*)addr);
  }
  float bv = -FLT_MAX; int bi = 0;
  #pragma unroll
  for (int mt = 0; mt < 2; ++mt)
    #pragma unroll
    for (int r = 0; r < 4; ++r) {
      float v = out2[mt][r];
      if (v > bv) { bv = v; bi = v0 + mt * 16 + l4 * 4 + r; }  // ascending idx
    }
  #pragma unroll
  for (int off = 16; off < 64; off <<= 1) {   // combine l4 groups (rows)
    float ov = __shfl_xor(bv, off, 64);
    int   oi = __shfl_xor(bi, off, 64);
    if (ov > bv || (ov == bv && oi < bi)) { bv = ov; bi = oi; }
  }
  if (l4 == 0) {
    pv[blockIdx.x * 64 + wave * 16 + l15] = bv;
    pidx[blockIdx.x * 64 + wave * 16 + l15] = bi;
  }
}

__global__ void k_final(const float* __restrict__ hf, float* __restrict__ dout) {
  int n = blockIdx.x * 256 + threadIdx.x;   // 131072; hf layout == out layout
  dout[OUT_H_OFF + n] = hf[n];
}

extern "C" void kernel_launch(void* const* d_in, const int* in_sizes, int n_in,
                              void* d_out, int out_size, void* d_ws, size_t ws_size,
                              hipStream_t stream) {
  const float* enc_h = (const float*)d_in[1];
  const float* emb   = (const float*)d_in[2];
  const float* w_ih  = (const float*)d_in[3];
  const float* w_hh  = (const float*)d_in[4];
  const float* b_ih  = (const float*)d_in[5];
  const float* b_hh  = (const float*)d_in[6];
  const float* out_w = (const float*)d_in[7];
  const float* out_b = (const float*)d_in[8];
  float* out = (float*)d_out;
  char* wsb = (char*)d_ws;

  u16* woh  = (u16*)(wsb + WOH_B);
  u16* wol  = (u16*)(wsb + WOL_B);
  u16* wihh = (u16*)(wsb + WIHH_B);
  u16* wihl = (u16*)(wsb + WIHL_B);
  u16* whhh = (u16*)(wsb + WHHH_B);
  u16* whhl = (u16*)(wsb + WHHL_B);
  u16* xh   = (u16*)(wsb + XH_B);
  u16* xl   = (u16*)(wsb + XL_B);
  u16* hbh  = (u16*)(wsb + HBH_B);
  u16* hbl  = (u16*)(wsb + HBL_B);
  float* hf = (float*)(wsb + HF_B);
  float* gt = (float*)(wsb + GT_B);
  float* pv = (float*)(wsb + PV_B);
  int* pidx = (int*)(wsb + PI_B);
  int* tok  = (int*)(wsb + TK_B);

  k_convert<<<4096, 256, 0, stream>>>(out_w, woh, wol, 8192000);
  k_convert<<<2048, 256, 0, stream>>>(w_ih, wihh, wihl, 1572864);
  k_convert<<<2048, 256, 0, stream>>>(w_hh, whhh, whhl, 1572864);
  k_init<<<512, 256, 0, stream>>>(enc_h, hf, hbh, hbl, tok);

  for (int t = 0; t < T_; ++t) {
    k_argmax_embed<<<1, 1024, 0, stream>>>(emb, pv, pidx, tok, xh, xl, t > 0);
    for (int l = 0; l < 2; ++l) {
      const u16* bxh = (l == 0) ? xh : hbh;   // layer 1 input = h[0]
      const u16* bxl = (l == 0) ? xl : hbl;
      k_gru<<<192, 256, 0, stream>>>(wihh + (size_t)l * 3145728, wihl + (size_t)l * 3145728,
                                     whhh + (size_t)l * 3145728, whhl + (size_t)l * 3145728,
                                     b_ih + l * 3072, b_hh + l * 3072,
                                     bxh, bxl, hbh + l * 65536, hbl + l * 65536, gt);
      k_gates<<<256, 256, 0, stream>>>(gt, hf + l * 65536, hbh + l * 65536, hbl + l * 65536);
    }
    k_logits<<<1000, 256, 0, stream>>>(woh, wol, out_b, hbh + 65536, hbl + 65536,
                                       pv, pidx, out, t);
  }
  k_final<<<512, 256, 0, stream>>>(hf, out);
}